// Round 1
// baseline (565.272 us; speedup 1.0000x reference)
//
#include <hip/hip_runtime.h>
#include <hip/hip_bf16.h>

#define V 8192
#define C 128

typedef __attribute__((ext_vector_type(8))) short short8;
typedef __attribute__((ext_vector_type(4))) float floatx4;

static __device__ __forceinline__ unsigned short f2bf(float f) {
    unsigned u = __float_as_uint(f);
    u += 0x7FFF + ((u >> 16) & 1);   // round-to-nearest-even
    return (unsigned short)(u >> 16);
}

// XMT[c][k] = bf16(x[k][c] * mass[k]); 64x64 LDS tiled transpose
__global__ __launch_bounds__(256) void prep_xmt(const float* __restrict__ x,
                                                const float* __restrict__ mass,
                                                unsigned short* __restrict__ XMT) {
    __shared__ float tile[64][65];
    const int k0 = blockIdx.x * 64;
    const int c0 = blockIdx.y * 64;
    const int t = threadIdx.x;
#pragma unroll
    for (int p = 0; p < 16; ++p) {
        int idx = p * 256 + t;
        int kk = idx >> 6, cc = idx & 63;
        tile[kk][cc] = x[(size_t)(k0 + kk) * C + (c0 + cc)] * mass[k0 + kk];
    }
    __syncthreads();
#pragma unroll
    for (int p = 0; p < 16; ++p) {
        int idx = p * 256 + t;
        int cc = idx >> 6, kk = idx & 63;
        XMT[(size_t)(c0 + cc) * V + (k0 + kk)] = f2bf(tile[kk][cc]);
    }
}

// coefsT[c][k] = exp(-(evals0[k/128]*t0[c] + evals1[k%128]*t1[c]))
__global__ __launch_bounds__(256) void prep_coef(const float* __restrict__ ev0,
                                                 const float* __restrict__ ev1,
                                                 const float* __restrict__ dt,
                                                 float* __restrict__ coefsT) {
    int id = blockIdx.x * 256 + threadIdx.x;
    int c = id >> 13;
    int k = id & (V - 1);
    float e = ev0[k >> 7] * dt[c] + ev1[k & 127] * dt[C + c];
    coefsT[(size_t)c * V + k] = expf(-e);
}

// GEMM1: S = E^T @ XM ; epilogue Y = coefs .* S written transposed bf16.
// A_eff[i][k] = E[k][i]; B_eff[k][c] = XMT[c][k].
// Block: iT = bx*32 rows, all 128 cols. 512 thr = 8 waves; wave w covers
// rows (w&1)*16, cols (w>>1)*32 (2 n-frags). BK=64.
__global__ __launch_bounds__(512) void gemm1(const float* __restrict__ E,
                                             const unsigned short* __restrict__ XMT,
                                             const float* __restrict__ coefsT,
                                             unsigned short* __restrict__ YT) {
    __shared__ __align__(16) unsigned short ldsA[32][72];
    __shared__ __align__(16) unsigned short ldsB[128][72];
    const int t = threadIdx.x;
    const int wave = t >> 6;
    const int lane = t & 63;
    const int q = lane >> 4;
    const int l15 = lane & 15;
    const int iT = blockIdx.x * 32;
    const int rW = (wave & 1) * 16;
    const int cW = (wave >> 1) * 32;

    floatx4 acc[2] = {{0.f, 0.f, 0.f, 0.f}, {0.f, 0.f, 0.f, 0.f}};

    const int a_kk = t >> 3;        // 0..63  (K row of A tile)
    const int a_m0 = (t & 7) * 4;   // 0..28  (4 contiguous i)
    const int b_c  = t >> 2;        // 0..127
    const int b_k0 = (t & 3) * 16;  // 0,16,32,48

    for (int k0 = 0; k0 < V; k0 += 64) {
        // A: ldsA[mm][kk] = bf16(E[k0+kk][iT+mm]) — transposed stage
        float4 av = *(const float4*)&E[(size_t)(k0 + a_kk) * V + iT + a_m0];
        // B: ldsB[c][kk] = XMT[c][k0+kk] — straight copy
        uint4 b0 = *(const uint4*)&XMT[(size_t)b_c * V + k0 + b_k0];
        uint4 b1 = *(const uint4*)&XMT[(size_t)b_c * V + k0 + b_k0 + 8];
        ldsA[a_m0 + 0][a_kk] = f2bf(av.x);
        ldsA[a_m0 + 1][a_kk] = f2bf(av.y);
        ldsA[a_m0 + 2][a_kk] = f2bf(av.z);
        ldsA[a_m0 + 3][a_kk] = f2bf(av.w);
        *(uint4*)&ldsB[b_c][b_k0] = b0;
        *(uint4*)&ldsB[b_c][b_k0 + 8] = b1;
        __syncthreads();
#pragma unroll
        for (int kk0 = 0; kk0 < 64; kk0 += 32) {
            short8 a  = *(const short8*)&ldsA[rW + l15][kk0 + q * 8];
            short8 bv0 = *(const short8*)&ldsB[cW + l15][kk0 + q * 8];
            short8 bv1 = *(const short8*)&ldsB[cW + 16 + l15][kk0 + q * 8];
            acc[0] = __builtin_amdgcn_mfma_f32_16x16x32_bf16(a, bv0, acc[0], 0, 0, 0);
            acc[1] = __builtin_amdgcn_mfma_f32_16x16x32_bf16(a, bv1, acc[1], 0, 0, 0);
        }
        __syncthreads();
    }
    // epilogue: D[row][col]: col = lane&15, row = q*4 + reg (verified layout)
    const int i0 = iT + rW + q * 4;
#pragma unroll
    for (int nf = 0; nf < 2; ++nf) {
        int c = cW + nf * 16 + l15;
        float4 cf = *(const float4*)&coefsT[(size_t)c * V + i0];
        ushort4 yv;
        yv.x = f2bf(acc[nf][0] * cf.x);
        yv.y = f2bf(acc[nf][1] * cf.y);
        yv.z = f2bf(acc[nf][2] * cf.z);
        yv.w = f2bf(acc[nf][3] * cf.w);
        *(ushort4*)&YT[(size_t)c * V + i0] = yv;
    }
}

// GEMM2: O = E @ Y. A_eff[i][k] = E[i][k]; B_eff[k][c] = YT[c][k].
__global__ __launch_bounds__(512) void gemm2(const float* __restrict__ E,
                                             const unsigned short* __restrict__ YT,
                                             float* __restrict__ out) {
    __shared__ __align__(16) unsigned short ldsA[32][72];
    __shared__ __align__(16) unsigned short ldsB[128][72];
    const int t = threadIdx.x;
    const int wave = t >> 6;
    const int lane = t & 63;
    const int q = lane >> 4;
    const int l15 = lane & 15;
    const int iT = blockIdx.x * 32;
    const int rW = (wave & 1) * 16;
    const int cW = (wave >> 1) * 32;

    floatx4 acc[2] = {{0.f, 0.f, 0.f, 0.f}, {0.f, 0.f, 0.f, 0.f}};

    const int a_mm = t >> 4;        // 0..31
    const int a_k0 = (t & 15) * 4;  // 0..60
    const int b_c  = t >> 2;        // 0..127
    const int b_k0 = (t & 3) * 16;  // 0,16,32,48

    for (int k0 = 0; k0 < V; k0 += 64) {
        // A: ldsA[mm][kk] = bf16(E[iT+mm][k0+kk]) — straight rows
        float4 av = *(const float4*)&E[(size_t)(iT + a_mm) * V + k0 + a_k0];
        uint4 b0 = *(const uint4*)&YT[(size_t)b_c * V + k0 + b_k0];
        uint4 b1 = *(const uint4*)&YT[(size_t)b_c * V + k0 + b_k0 + 8];
        ushort4 aw;
        aw.x = f2bf(av.x); aw.y = f2bf(av.y); aw.z = f2bf(av.z); aw.w = f2bf(av.w);
        *(ushort4*)&ldsA[a_mm][a_k0] = aw;
        *(uint4*)&ldsB[b_c][b_k0] = b0;
        *(uint4*)&ldsB[b_c][b_k0 + 8] = b1;
        __syncthreads();
#pragma unroll
        for (int kk0 = 0; kk0 < 64; kk0 += 32) {
            short8 a  = *(const short8*)&ldsA[rW + l15][kk0 + q * 8];
            short8 bv0 = *(const short8*)&ldsB[cW + l15][kk0 + q * 8];
            short8 bv1 = *(const short8*)&ldsB[cW + 16 + l15][kk0 + q * 8];
            acc[0] = __builtin_amdgcn_mfma_f32_16x16x32_bf16(a, bv0, acc[0], 0, 0, 0);
            acc[1] = __builtin_amdgcn_mfma_f32_16x16x32_bf16(a, bv1, acc[1], 0, 0, 0);
        }
        __syncthreads();
    }
    const int i0 = iT + rW + q * 4;
#pragma unroll
    for (int nf = 0; nf < 2; ++nf) {
        int c = cW + nf * 16 + l15;
        out[(size_t)(i0 + 0) * C + c] = acc[nf][0];
        out[(size_t)(i0 + 1) * C + c] = acc[nf][1];
        out[(size_t)(i0 + 2) * C + c] = acc[nf][2];
        out[(size_t)(i0 + 3) * C + c] = acc[nf][3];
    }
}

extern "C" void kernel_launch(void* const* d_in, const int* in_sizes, int n_in,
                              void* d_out, int out_size, void* d_ws, size_t ws_size,
                              hipStream_t stream) {
    const float* x    = (const float*)d_in[0];
    const float* mass = (const float*)d_in[3];
    const float* ev0  = (const float*)d_in[4];
    const float* ev1  = (const float*)d_in[5];
    const float* E    = (const float*)d_in[6];
    const float* dt   = (const float*)d_in[7];
    float* out = (float*)d_out;

    // ws layout: XMT (2 MB) | YT (2 MB) | coefsT (4 MB)  => 8 MB total
    unsigned short* XMT = (unsigned short*)d_ws;
    unsigned short* YT  = XMT + (size_t)V * C;
    float* coefsT = (float*)(YT + (size_t)V * C);

    prep_xmt<<<dim3(V / 64, C / 64), 256, 0, stream>>>(x, mass, XMT);
    prep_coef<<<(V * C) / 256, 256, 0, stream>>>(ev0, ev1, dt, coefsT);
    gemm1<<<V / 32, 512, 0, stream>>>(E, XMT, coefsT, YT);
    gemm2<<<V / 32, 512, 0, stream>>>(E, YT, out);
}

// Round 2
// 560.052 us; speedup vs baseline: 1.0093x; 1.0093x over previous
//
#include <hip/hip_runtime.h>
#include <hip/hip_bf16.h>
#include <stdint.h>

#define V 8192
#define C 128
#define KS 8
#define KCH (V / KS)   // 1024
#define BK 64

typedef __attribute__((ext_vector_type(8))) short short8;
typedef __attribute__((ext_vector_type(4))) float floatx4;

typedef unsigned int __attribute__((address_space(1))) gas_u32;
typedef unsigned int __attribute__((address_space(3))) las_u32;
#define GLD16(g, l) __builtin_amdgcn_global_load_lds((const gas_u32*)(g), (las_u32*)(l), 16, 0, 0)

static __device__ __forceinline__ unsigned short f2bf(float f) {
    unsigned u = __float_as_uint(f);
    u += 0x7FFF + ((u >> 16) & 1);   // RNE
    return (unsigned short)(u >> 16);
}

// ---------------------------------------------------------------- prep kernels
// XMT[c][k] = bf16(x[k][c] * mass[k]); 64x64 LDS tiled transpose
__global__ __launch_bounds__(256) void prep_xmt(const float* __restrict__ x,
                                                const float* __restrict__ mass,
                                                unsigned short* __restrict__ XMT) {
    __shared__ float tile[64][65];
    const int k0 = blockIdx.x * 64;
    const int c0 = blockIdx.y * 64;
    const int t = threadIdx.x;
#pragma unroll
    for (int p = 0; p < 16; ++p) {
        int idx = p * 256 + t;
        int kk = idx >> 6, cc = idx & 63;
        tile[kk][cc] = x[(size_t)(k0 + kk) * C + (c0 + cc)] * mass[k0 + kk];
    }
    __syncthreads();
#pragma unroll
    for (int p = 0; p < 16; ++p) {
        int idx = p * 256 + t;
        int cc = idx >> 6, kk = idx & 63;
        XMT[(size_t)(c0 + cc) * V + (k0 + kk)] = f2bf(tile[kk][cc]);
    }
}

// Ebf[v][j] = bf16(E[v][j]); EbfT[j][v] = bf16(E[v][j]) via 64x64 LDS transpose
__global__ __launch_bounds__(256) void prep_ebf(const float* __restrict__ E,
                                                unsigned short* __restrict__ Ebf,
                                                unsigned short* __restrict__ EbfT) {
    __shared__ unsigned short tile[64][68];
    const int v0 = blockIdx.x * 64;
    const int j0 = blockIdx.y * 64;
    const int t = threadIdx.x;
#pragma unroll
    for (int rep = 0; rep < 4; ++rep) {
        int id = rep * 256 + t;
        int vv = id >> 4;         // 0..63
        int f4 = id & 15;         // j-group
        float4 e = *(const float4*)&E[(size_t)(v0 + vv) * V + j0 + f4 * 4];
        ushort4 b;
        b.x = f2bf(e.x); b.y = f2bf(e.y); b.z = f2bf(e.z); b.w = f2bf(e.w);
        *(ushort4*)&Ebf[(size_t)(v0 + vv) * V + j0 + f4 * 4] = b;
        *(ushort4*)&tile[vv][f4 * 4] = b;
    }
    __syncthreads();
#pragma unroll
    for (int rep = 0; rep < 4; ++rep) {
        int id = rep * 256 + t;
        int jj = id >> 4;         // 0..63
        int v4 = (id & 15) * 4;   // v-group
        ushort4 b;
        b.x = tile[v4 + 0][jj];
        b.y = tile[v4 + 1][jj];
        b.z = tile[v4 + 2][jj];
        b.w = tile[v4 + 3][jj];
        *(ushort4*)&EbfT[(size_t)(j0 + jj) * V + v0 + v4] = b;
    }
}

// ---------------------------------------------------------------- shared GEMM
// P[ks][m][n] (+)= A[m][k] * B[n][k] over k-chunk ks.
// A: [8192][8192] bf16 k-major.  B: [128][8192] bf16 k-major.
// 128x128 tile, BK=64, 256 thr (4 waves, 64x64 each), global_load_lds staging
// with XOR-swizzled packed LDS (chunk pos p = c ^ (row&7)).
__global__ __launch_bounds__(256, 2) void gemm_bf16(const unsigned short* __restrict__ A,
                                                    const unsigned short* __restrict__ B,
                                                    float* __restrict__ P) {
    __shared__ __align__(16) unsigned short ldsA[128 * BK];
    __shared__ __align__(16) unsigned short ldsB[128 * BK];
    const int bx = blockIdx.x;
    const int ks = bx & (KS - 1);        // XCD r gets ks=r -> B k-chunk L2-resident
    const int m0 = (bx >> 3) * 128;
    const int k_base = ks * KCH;
    const int t = threadIdx.x;
    const int w = t >> 6;
    const int lane = t & 63;
    const int q = lane >> 4;
    const int l15 = lane & 15;
    const int wm = (w & 1) * 64;
    const int wn = (w >> 1) * 64;
    const int srow = lane >> 3;          // staging: row within 8-row group
    const int spos = lane & 7;           // staging: 16B chunk position

    floatx4 acc[4][4] = {};

    for (int k0 = k_base; k0 < k_base + KCH; k0 += BK) {
        __syncthreads();  // previous iter's frag reads done before overwrite
#pragma unroll
        for (int j = 0; j < 4; ++j) {
            int r = 32 * w + 8 * j + srow;
            int c = spos ^ (r & 7);
            GLD16(&A[(size_t)(m0 + r) * V + k0 + 8 * c], &ldsA[(32 * w + 8 * j) * BK]);
            GLD16(&B[(size_t)r * V + k0 + 8 * c], &ldsB[(32 * w + 8 * j) * BK]);
        }
        __syncthreads();  // drains vmcnt(0): staging complete
#pragma unroll
        for (int kk = 0; kk < BK; kk += 32) {
            short8 af[4], bf[4];
#pragma unroll
            for (int mi = 0; mi < 4; ++mi) {
                int m = wm + mi * 16 + l15;
                int cpos = ((kk >> 3) + q) ^ (m & 7);
                af[mi] = *(const short8*)&ldsA[m * BK + 8 * cpos];
            }
#pragma unroll
            for (int ni = 0; ni < 4; ++ni) {
                int n = wn + ni * 16 + l15;
                int cpos = ((kk >> 3) + q) ^ (n & 7);
                bf[ni] = *(const short8*)&ldsB[n * BK + 8 * cpos];
            }
#pragma unroll
            for (int mi = 0; mi < 4; ++mi)
#pragma unroll
                for (int ni = 0; ni < 4; ++ni)
                    acc[mi][ni] = __builtin_amdgcn_mfma_f32_16x16x32_bf16(af[mi], bf[ni], acc[mi][ni], 0, 0, 0);
        }
    }
    float* Pks = P + (size_t)ks * V * C;
#pragma unroll
    for (int mi = 0; mi < 4; ++mi) {
        int mrow = m0 + wm + mi * 16 + q * 4;
#pragma unroll
        for (int ni = 0; ni < 4; ++ni) {
            int n = wn + ni * 16 + l15;
#pragma unroll
            for (int r = 0; r < 4; ++r)
                Pks[(size_t)(mrow + r) * C + n] = acc[mi][ni][r];
        }
    }
}

// ---------------------------------------------------------------- reductions
// YT[c][j] = bf16(coef(j,c) * sum_ks P[ks][j][c])   (LDS transpose)
__global__ __launch_bounds__(256) void red1(const float* __restrict__ P,
                                            const float* __restrict__ ev0,
                                            const float* __restrict__ ev1,
                                            const float* __restrict__ dt,
                                            unsigned short* __restrict__ YT) {
    __shared__ float tile[64][65];
    const int j0 = blockIdx.x * 64;
    const int c0 = blockIdx.y * 64;
    const int t = threadIdx.x;
#pragma unroll
    for (int rep = 0; rep < 16; ++rep) {
        int id = rep * 256 + t;
        int jj = id >> 6, cc = id & 63;
        float s = 0.f;
#pragma unroll
        for (int k = 0; k < KS; ++k)
            s += P[((size_t)k * V + j0 + jj) * C + c0 + cc];
        int j = j0 + jj, c = c0 + cc;
        float coef = __expf(-(ev0[j >> 7] * dt[c] + ev1[j & 127] * dt[C + c]));
        tile[jj][cc] = s * coef;
    }
    __syncthreads();
#pragma unroll
    for (int rep = 0; rep < 16; ++rep) {
        int id = rep * 256 + t;
        int cc = id >> 6, jj = id & 63;
        YT[(size_t)(c0 + cc) * V + j0 + jj] = f2bf(tile[jj][cc]);
    }
}

__global__ __launch_bounds__(256) void red2(const float* __restrict__ P,
                                            float* __restrict__ out) {
    int id = blockIdx.x * 256 + threadIdx.x;
    float s = 0.f;
#pragma unroll
    for (int k = 0; k < KS; ++k) s += P[(size_t)k * V * C + id];
    out[id] = s;
}

// ---------------------------------------------------------------- fallback (round-1 verified path)
__global__ __launch_bounds__(256) void prep_coef(const float* __restrict__ ev0,
                                                 const float* __restrict__ ev1,
                                                 const float* __restrict__ dt,
                                                 float* __restrict__ coefsT) {
    int id = blockIdx.x * 256 + threadIdx.x;
    int c = id >> 13;
    int k = id & (V - 1);
    float e = ev0[k >> 7] * dt[c] + ev1[k & 127] * dt[C + c];
    coefsT[(size_t)c * V + k] = expf(-e);
}

__global__ __launch_bounds__(512) void gemm1_old(const float* __restrict__ E,
                                                 const unsigned short* __restrict__ XMT,
                                                 const float* __restrict__ coefsT,
                                                 unsigned short* __restrict__ YT) {
    __shared__ __align__(16) unsigned short ldsA[32][72];
    __shared__ __align__(16) unsigned short ldsB[128][72];
    const int t = threadIdx.x;
    const int wave = t >> 6;
    const int lane = t & 63;
    const int q = lane >> 4;
    const int l15 = lane & 15;
    const int iT = blockIdx.x * 32;
    const int rW = (wave & 1) * 16;
    const int cW = (wave >> 1) * 32;
    floatx4 acc[2] = {{0.f, 0.f, 0.f, 0.f}, {0.f, 0.f, 0.f, 0.f}};
    const int a_kk = t >> 3;
    const int a_m0 = (t & 7) * 4;
    const int b_c  = t >> 2;
    const int b_k0 = (t & 3) * 16;
    for (int k0 = 0; k0 < V; k0 += 64) {
        float4 av = *(const float4*)&E[(size_t)(k0 + a_kk) * V + iT + a_m0];
        uint4 b0 = *(const uint4*)&XMT[(size_t)b_c * V + k0 + b_k0];
        uint4 b1 = *(const uint4*)&XMT[(size_t)b_c * V + k0 + b_k0 + 8];
        ldsA[a_m0 + 0][a_kk] = f2bf(av.x);
        ldsA[a_m0 + 1][a_kk] = f2bf(av.y);
        ldsA[a_m0 + 2][a_kk] = f2bf(av.z);
        ldsA[a_m0 + 3][a_kk] = f2bf(av.w);
        *(uint4*)&ldsB[b_c][b_k0] = b0;
        *(uint4*)&ldsB[b_c][b_k0 + 8] = b1;
        __syncthreads();
#pragma unroll
        for (int kk0 = 0; kk0 < 64; kk0 += 32) {
            short8 a  = *(const short8*)&ldsA[rW + l15][kk0 + q * 8];
            short8 bv0 = *(const short8*)&ldsB[cW + l15][kk0 + q * 8];
            short8 bv1 = *(const short8*)&ldsB[cW + 16 + l15][kk0 + q * 8];
            acc[0] = __builtin_amdgcn_mfma_f32_16x16x32_bf16(a, bv0, acc[0], 0, 0, 0);
            acc[1] = __builtin_amdgcn_mfma_f32_16x16x32_bf16(a, bv1, acc[1], 0, 0, 0);
        }
        __syncthreads();
    }
    const int i0 = iT + rW + q * 4;
#pragma unroll
    for (int nf = 0; nf < 2; ++nf) {
        int c = cW + nf * 16 + l15;
        float4 cf = *(const float4*)&coefsT[(size_t)c * V + i0];
        ushort4 yv;
        yv.x = f2bf(acc[nf][0] * cf.x);
        yv.y = f2bf(acc[nf][1] * cf.y);
        yv.z = f2bf(acc[nf][2] * cf.z);
        yv.w = f2bf(acc[nf][3] * cf.w);
        *(ushort4*)&YT[(size_t)c * V + i0] = yv;
    }
}

__global__ __launch_bounds__(512) void gemm2_old(const float* __restrict__ E,
                                                 const unsigned short* __restrict__ YT,
                                                 float* __restrict__ out) {
    __shared__ __align__(16) unsigned short ldsA[32][72];
    __shared__ __align__(16) unsigned short ldsB[128][72];
    const int t = threadIdx.x;
    const int wave = t >> 6;
    const int lane = t & 63;
    const int q = lane >> 4;
    const int l15 = lane & 15;
    const int iT = blockIdx.x * 32;
    const int rW = (wave & 1) * 16;
    const int cW = (wave >> 1) * 32;
    floatx4 acc[2] = {{0.f, 0.f, 0.f, 0.f}, {0.f, 0.f, 0.f, 0.f}};
    const int a_mm = t >> 4;
    const int a_k0 = (t & 15) * 4;
    const int b_c  = t >> 2;
    const int b_k0 = (t & 3) * 16;
    for (int k0 = 0; k0 < V; k0 += 64) {
        float4 av = *(const float4*)&E[(size_t)(iT + a_mm) * V + k0 + a_k0];
        uint4 b0 = *(const uint4*)&YT[(size_t)b_c * V + k0 + b_k0];
        uint4 b1 = *(const uint4*)&YT[(size_t)b_c * V + k0 + b_k0 + 8];
        ushort4 aw;
        aw.x = f2bf(av.x); aw.y = f2bf(av.y); aw.z = f2bf(av.z); aw.w = f2bf(av.w);
        *(ushort4*)&ldsA[a_mm][a_k0] = aw;
        *(uint4*)&ldsB[b_c][b_k0] = b0;
        *(uint4*)&ldsB[b_c][b_k0 + 8] = b1;
        __syncthreads();
#pragma unroll
        for (int kk0 = 0; kk0 < 64; kk0 += 32) {
            short8 a  = *(const short8*)&ldsA[rW + l15][kk0 + q * 8];
            short8 bv0 = *(const short8*)&ldsB[cW + l15][kk0 + q * 8];
            short8 bv1 = *(const short8*)&ldsB[cW + 16 + l15][kk0 + q * 8];
            acc[0] = __builtin_amdgcn_mfma_f32_16x16x32_bf16(a, bv0, acc[0], 0, 0, 0);
            acc[1] = __builtin_amdgcn_mfma_f32_16x16x32_bf16(a, bv1, acc[1], 0, 0, 0);
        }
        __syncthreads();
    }
    const int i0 = iT + rW + q * 4;
#pragma unroll
    for (int nf = 0; nf < 2; ++nf) {
        int c = cW + nf * 16 + l15;
        out[(size_t)(i0 + 0) * C + c] = acc[nf][0];
        out[(size_t)(i0 + 1) * C + c] = acc[nf][1];
        out[(size_t)(i0 + 2) * C + c] = acc[nf][2];
        out[(size_t)(i0 + 3) * C + c] = acc[nf][3];
    }
}

// ---------------------------------------------------------------- launch
extern "C" void kernel_launch(void* const* d_in, const int* in_sizes, int n_in,
                              void* d_out, int out_size, void* d_ws, size_t ws_size,
                              hipStream_t stream) {
    const float* x    = (const float*)d_in[0];
    const float* mass = (const float*)d_in[3];
    const float* ev0  = (const float*)d_in[4];
    const float* ev1  = (const float*)d_in[5];
    const float* E    = (const float*)d_in[6];
    const float* dt   = (const float*)d_in[7];
    float* out = (float*)d_out;

    // fast-path ws layout: XMT(2M) | YT(2M) | Ebf(128M) | EbfT(128M) | P(32M)
    const size_t szXMT = (size_t)V * C;                 // shorts
    const size_t szE   = (size_t)V * V;                 // shorts
    const size_t needed = (2 * szXMT + 2 * szE) * 2 + (size_t)KS * V * C * 4;

    unsigned short* XMT = (unsigned short*)d_ws;
    unsigned short* YT  = XMT + szXMT;

    if (ws_size >= needed) {
        unsigned short* Ebf  = YT + szXMT;
        unsigned short* EbfT = Ebf + szE;
        float* P = (float*)(EbfT + szE);

        prep_xmt<<<dim3(V / 64, C / 64), 256, 0, stream>>>(x, mass, XMT);
        prep_ebf<<<dim3(V / 64, V / 64), 256, 0, stream>>>(E, Ebf, EbfT);
        gemm_bf16<<<(V / 128) * KS, 256, 0, stream>>>(EbfT, XMT, P);   // x_spec[j][c]
        red1<<<dim3(V / 64, C / 64), 256, 0, stream>>>(P, ev0, ev1, dt, YT);
        gemm_bf16<<<(V / 128) * KS, 256, 0, stream>>>(Ebf, YT, P);     // out partials
        red2<<<(V * C) / 256, 256, 0, stream>>>(P, out);
    } else {
        // round-1 verified fallback (needs 8 MiB)
        float* coefsT = (float*)(YT + szXMT);
        prep_xmt<<<dim3(V / 64, C / 64), 256, 0, stream>>>(x, mass, XMT);
        prep_coef<<<(V * C) / 256, 256, 0, stream>>>(ev0, ev1, dt, coefsT);
        gemm1_old<<<V / 32, 512, 0, stream>>>(E, XMT, coefsT, YT);
        gemm2_old<<<V / 32, 512, 0, stream>>>(E, YT, out);
    }
}

// Round 3
// 464.717 us; speedup vs baseline: 1.2164x; 1.2051x over previous
//
#include <hip/hip_runtime.h>
#include <hip/hip_bf16.h>
#include <stdint.h>

#define V 8192
#define C 128
#define KS 8
#define KCH (V / KS)   // 1024
#define BK 64

typedef __attribute__((ext_vector_type(8))) short short8;
typedef __attribute__((ext_vector_type(4))) float floatx4;

typedef unsigned int __attribute__((address_space(1))) gas_u32;
typedef unsigned int __attribute__((address_space(3))) las_u32;
#define GLD16(g, l) __builtin_amdgcn_global_load_lds((const gas_u32*)(g), (las_u32*)(l), 16, 0, 0)

static __device__ __forceinline__ unsigned short f2bf(float f) {
    unsigned u = __float_as_uint(f);
    u += 0x7FFF + ((u >> 16) & 1);   // RNE
    return (unsigned short)(u >> 16);
}

// ---------------------------------------------------------------- prep
// XMT[c][k] = bf16(x[k][c] * mass[k]); 64x64 LDS tiled transpose
__global__ __launch_bounds__(256) void prep_xmt(const float* __restrict__ x,
                                                const float* __restrict__ mass,
                                                unsigned short* __restrict__ XMT) {
    __shared__ float tile[64][65];
    const int k0 = blockIdx.x * 64;
    const int c0 = blockIdx.y * 64;
    const int t = threadIdx.x;
#pragma unroll
    for (int p = 0; p < 16; ++p) {
        int idx = p * 256 + t;
        int kk = idx >> 6, cc = idx & 63;
        tile[kk][cc] = x[(size_t)(k0 + kk) * C + (c0 + cc)] * mass[k0 + kk];
    }
    __syncthreads();
#pragma unroll
    for (int p = 0; p < 16; ++p) {
        int idx = p * 256 + t;
        int cc = idx >> 6, kk = idx & 63;
        XMT[(size_t)(c0 + cc) * V + (k0 + kk)] = f2bf(tile[kk][cc]);
    }
}

// ---------------------------------------------------------------- GEMM1
// P1[ks][c][j] = sum_{v in chunk ks} XMT[c][v] * E[v][j]
// A = XMT bf16 k-major (GLD16).  B = fp32 E, transpose fused into staging.
// 128x128 tile (m=c full, n=j), BK=64, 4 waves of 64x64.
__global__ __launch_bounds__(256, 3) void gemm1_fused(const unsigned short* __restrict__ XMT,
                                                      const float* __restrict__ E,
                                                      float* __restrict__ P1) {
    __shared__ __align__(16) unsigned short ldsA[128 * BK];  // [c][v-swizzled]
    __shared__ __align__(16) unsigned short ldsB[128 * BK];  // [j][v-swizzled]
    const int bx = blockIdx.x;
    const int ks = bx & (KS - 1);
    const int n0 = (bx >> 3) * 128;
    const int kb = ks * KCH;
    const int t = threadIdx.x;
    const int w = t >> 6;
    const int lane = t & 63;
    const int q = lane >> 4;
    const int l15 = lane & 15;
    const int wm = (w & 1) * 64;
    const int wn = (w >> 1) * 64;
    const int srow = lane >> 3;
    const int spos = lane & 7;
    // B-staging thread map: 8 v's (contiguous) x 4 j's per thread
    const int vg = t & 7;        // v-block: v = vg*8 + rr
    const int jg = t >> 3;       // j-block: j = jg*4 + jj  (0..31 -> 0..127)

    floatx4 acc[4][4] = {};

    for (int k0 = kb; k0 < kb + KCH; k0 += BK) {
        __syncthreads();  // prior frag reads done before overwrite
        // A: XMT rows (c), packed 128B rows, XOR swizzle
#pragma unroll
        for (int j = 0; j < 4; ++j) {
            int r = 32 * w + 8 * j + srow;
            int cp = spos ^ (r & 7);
            GLD16(&XMT[(size_t)r * V + k0 + 8 * cp], &ldsA[(32 * w + 8 * j) * BK]);
        }
        // B: fp32 E [v][j] -> bf16 LDS [j][v], register transpose
        float4 ld[8];
#pragma unroll
        for (int rr = 0; rr < 8; ++rr)
            ld[rr] = *(const float4*)&E[(size_t)(k0 + vg * 8 + rr) * V + n0 + jg * 4];
        const float* lf = (const float*)ld;
#pragma unroll
        for (int jj = 0; jj < 4; ++jj) {
            int j = jg * 4 + jj;
            int phys = vg ^ (j & 7);
            short8 b;
#pragma unroll
            for (int rr = 0; rr < 8; ++rr) b[rr] = (short)f2bf(lf[rr * 4 + jj]);
            *(short8*)&ldsB[j * BK + phys * 8] = b;
        }
        __syncthreads();  // drains vmcnt(0): staging complete
#pragma unroll
        for (int kk = 0; kk < BK; kk += 32) {
            short8 af[4], bf[4];
#pragma unroll
            for (int mi = 0; mi < 4; ++mi) {
                int m = wm + mi * 16 + l15;
                int cpos = ((kk >> 3) + q) ^ (m & 7);
                af[mi] = *(const short8*)&ldsA[m * BK + 8 * cpos];
            }
#pragma unroll
            for (int ni = 0; ni < 4; ++ni) {
                int n = wn + ni * 16 + l15;
                int cpos = ((kk >> 3) + q) ^ (n & 7);
                bf[ni] = *(const short8*)&ldsB[n * BK + 8 * cpos];
            }
#pragma unroll
            for (int mi = 0; mi < 4; ++mi)
#pragma unroll
                for (int ni = 0; ni < 4; ++ni)
                    acc[mi][ni] = __builtin_amdgcn_mfma_f32_16x16x32_bf16(af[mi], bf[ni], acc[mi][ni], 0, 0, 0);
        }
    }
    float* Pks = P1 + (size_t)ks * C * V;
#pragma unroll
    for (int mi = 0; mi < 4; ++mi) {
        int mrow = wm + mi * 16 + q * 4;
#pragma unroll
        for (int ni = 0; ni < 4; ++ni) {
            int n = n0 + wn + ni * 16 + l15;
#pragma unroll
            for (int r = 0; r < 4; ++r)
                Pks[(size_t)(mrow + r) * V + n] = acc[mi][ni][r];
        }
    }
}

// ---------------------------------------------------------------- GEMM2
// P2[ks][i][c] = sum_{j in chunk ks} E[i][j] * YT[c][j]
// A = fp32 E natural row-major (convert during staging). B = YT bf16 (GLD16).
__global__ __launch_bounds__(256, 3) void gemm2_fused(const float* __restrict__ E,
                                                      const unsigned short* __restrict__ YT,
                                                      float* __restrict__ P2) {
    __shared__ __align__(16) unsigned short ldsA[128 * BK];  // [i][j-swizzled]
    __shared__ __align__(16) unsigned short ldsB[128 * BK];  // [c][j-swizzled]
    const int bx = blockIdx.x;
    const int ks = bx & (KS - 1);
    const int m0 = (bx >> 3) * 128;
    const int kb = ks * KCH;
    const int t = threadIdx.x;
    const int w = t >> 6;
    const int lane = t & 63;
    const int q = lane >> 4;
    const int l15 = lane & 15;
    const int wm = (w & 1) * 64;
    const int wn = (w >> 1) * 64;
    const int srow = lane >> 3;
    const int spos = lane & 7;
    // A-staging map: thread covers rows r16, r16+64; 16 contiguous k each
    const int r16 = t >> 2;      // 0..63
    const int p = t & 3;         // k quarter: k = p*16 + ...

    floatx4 acc[4][4] = {};

    for (int k0 = kb; k0 < kb + KCH; k0 += BK) {
        __syncthreads();
        // B: YT rows (c) via GLD16
#pragma unroll
        for (int j = 0; j < 4; ++j) {
            int r = 32 * w + 8 * j + srow;
            int cp = spos ^ (r & 7);
            GLD16(&YT[(size_t)r * V + k0 + 8 * cp], &ldsB[(32 * w + 8 * j) * BK]);
        }
        // A: fp32 E rows -> bf16 LDS, straight (no transpose)
#pragma unroll
        for (int half = 0; half < 2; ++half) {
            int row = r16 + half * 64;
            float4 la[4];
#pragma unroll
            for (int u = 0; u < 4; ++u)
                la[u] = *(const float4*)&E[(size_t)(m0 + row) * V + k0 + p * 16 + u * 4];
            const float* lf = (const float*)la;
#pragma unroll
            for (int cc = 0; cc < 2; ++cc) {
                int phys = (2 * p + cc) ^ (row & 7);
                short8 av;
#pragma unroll
                for (int e = 0; e < 8; ++e) av[e] = (short)f2bf(lf[cc * 8 + e]);
                *(short8*)&ldsA[row * BK + phys * 8] = av;
            }
        }
        __syncthreads();
#pragma unroll
        for (int kk = 0; kk < BK; kk += 32) {
            short8 af[4], bf[4];
#pragma unroll
            for (int mi = 0; mi < 4; ++mi) {
                int m = wm + mi * 16 + l15;
                int cpos = ((kk >> 3) + q) ^ (m & 7);
                af[mi] = *(const short8*)&ldsA[m * BK + 8 * cpos];
            }
#pragma unroll
            for (int ni = 0; ni < 4; ++ni) {
                int n = wn + ni * 16 + l15;
                int cpos = ((kk >> 3) + q) ^ (n & 7);
                bf[ni] = *(const short8*)&ldsB[n * BK + 8 * cpos];
            }
#pragma unroll
            for (int mi = 0; mi < 4; ++mi)
#pragma unroll
                for (int ni = 0; ni < 4; ++ni)
                    acc[mi][ni] = __builtin_amdgcn_mfma_f32_16x16x32_bf16(af[mi], bf[ni], acc[mi][ni], 0, 0, 0);
        }
    }
    float* Pks = P2 + (size_t)ks * V * C;
#pragma unroll
    for (int mi = 0; mi < 4; ++mi) {
        int mrow = m0 + wm + mi * 16 + q * 4;
#pragma unroll
        for (int ni = 0; ni < 4; ++ni) {
            int n = wn + ni * 16 + l15;
#pragma unroll
            for (int r = 0; r < 4; ++r)
                Pks[(size_t)(mrow + r) * C + n] = acc[mi][ni][r];
        }
    }
}

// ---------------------------------------------------------------- reductions
// YT[c][j] = bf16(coef(j,c) * sum_ks P1[ks][c][j]) — no transpose needed
__global__ __launch_bounds__(256) void red1(const float* __restrict__ P1,
                                            const float* __restrict__ ev0,
                                            const float* __restrict__ ev1,
                                            const float* __restrict__ dt,
                                            unsigned short* __restrict__ YT) {
    int id = blockIdx.x * 256 + threadIdx.x;   // 131072 threads
    int c = id >> 10;
    int j0 = (id & 1023) * 8;
    float s[8] = {};
#pragma unroll
    for (int ks = 0; ks < KS; ++ks) {
        const float* row = &P1[((size_t)ks * C + c) * V + j0];
        float4 a = *(const float4*)row;
        float4 b = *(const float4*)(row + 4);
        s[0] += a.x; s[1] += a.y; s[2] += a.z; s[3] += a.w;
        s[4] += b.x; s[5] += b.y; s[6] += b.z; s[7] += b.w;
    }
    float t0 = dt[c], t1 = dt[C + c];
    float a0 = ev0[j0 >> 7] * t0;   // constant across the 8 j's (aligned)
    short8 yv;
#pragma unroll
    for (int jj = 0; jj < 8; ++jj) {
        float coef = __expf(-(a0 + ev1[(j0 + jj) & 127] * t1));
        yv[jj] = (short)f2bf(s[jj] * coef);
    }
    *(short8*)&YT[(size_t)c * V + j0] = yv;
}

__global__ __launch_bounds__(256) void red2(const float* __restrict__ P2,
                                            float* __restrict__ out) {
    int id = blockIdx.x * 256 + threadIdx.x;   // V*C/4 threads
    size_t off = (size_t)id * 4;
    float4 s = {0.f, 0.f, 0.f, 0.f};
#pragma unroll
    for (int ks = 0; ks < KS; ++ks) {
        float4 v = *(const float4*)&P2[(size_t)ks * V * C + off];
        s.x += v.x; s.y += v.y; s.z += v.z; s.w += v.w;
    }
    *(float4*)&out[off] = s;
}

// ---------------------------------------------------------------- launch
extern "C" void kernel_launch(void* const* d_in, const int* in_sizes, int n_in,
                              void* d_out, int out_size, void* d_ws, size_t ws_size,
                              hipStream_t stream) {
    const float* x    = (const float*)d_in[0];
    const float* mass = (const float*)d_in[3];
    const float* ev0  = (const float*)d_in[4];
    const float* ev1  = (const float*)d_in[5];
    const float* E    = (const float*)d_in[6];
    const float* dt   = (const float*)d_in[7];
    float* out = (float*)d_out;

    // ws: XMT (2 MB) | YT (2 MB) | P (32 MB, reused by both GEMMs)
    unsigned short* XMT = (unsigned short*)d_ws;
    unsigned short* YT  = XMT + (size_t)V * C;
    float* P = (float*)(YT + (size_t)V * C);

    prep_xmt<<<dim3(V / 64, C / 64), 256, 0, stream>>>(x, mass, XMT);
    gemm1_fused<<<(V / 128) * KS, 256, 0, stream>>>(XMT, E, P);
    red1<<<(C * V / 8) / 256, 256, 0, stream>>>(P, ev0, ev1, dt, YT);
    gemm2_fused<<<(V / 128) * KS, 256, 0, stream>>>(E, YT, P);
    red2<<<(V * C / 4) / 256, 256, 0, stream>>>(P, out);
}

// Round 5
// 457.142 us; speedup vs baseline: 1.2365x; 1.0166x over previous
//
#include <hip/hip_runtime.h>
#include <hip/hip_bf16.h>
#include <stdint.h>

#define V 8192
#define C 128
#define KS 8
#define KCH (V / KS)   // 1024
#define BK 64
#define NI (KCH / BK)  // 16 k-iters per chunk

typedef __attribute__((ext_vector_type(8))) short short8;
typedef __attribute__((ext_vector_type(4))) float floatx4;

static __device__ __forceinline__ unsigned short f2bf(float f) {
    unsigned u = __float_as_uint(f);
    u += 0x7FFF + ((u >> 16) & 1);   // RNE
    return (unsigned short)(u >> 16);
}

// ---------------------------------------------------------------- prep
// XMT[c][k] = bf16(x[k][c] * mass[k]); 64x64 LDS tiled transpose
__global__ __launch_bounds__(256) void prep_xmt(const float* __restrict__ x,
                                                const float* __restrict__ mass,
                                                unsigned short* __restrict__ XMT) {
    __shared__ float tile[64][65];
    const int k0 = blockIdx.x * 64;
    const int c0 = blockIdx.y * 64;
    const int t = threadIdx.x;
#pragma unroll
    for (int p = 0; p < 16; ++p) {
        int idx = p * 256 + t;
        int kk = idx >> 6, cc = idx & 63;
        tile[kk][cc] = x[(size_t)(k0 + kk) * C + (c0 + cc)] * mass[k0 + kk];
    }
    __syncthreads();
#pragma unroll
    for (int p = 0; p < 16; ++p) {
        int idx = p * 256 + t;
        int cc = idx >> 6, kk = idx & 63;
        XMT[(size_t)(c0 + cc) * V + (k0 + kk)] = f2bf(tile[kk][cc]);
    }
}

// Shared MFMA inner step (reads swizzled LDS, 32 MFMA/wave)
#define MFMA_BODY                                                                   \
    {                                                                               \
        _Pragma("unroll")                                                           \
        for (int kk = 0; kk < BK; kk += 32) {                                       \
            short8 af[4], bf[4];                                                    \
            _Pragma("unroll")                                                       \
            for (int mi = 0; mi < 4; ++mi) {                                        \
                int m = wm + mi * 16 + l15;                                         \
                int cpos = ((kk >> 3) + q) ^ (m & 7);                               \
                af[mi] = *(const short8*)&ldsA[m * BK + 8 * cpos];                  \
            }                                                                       \
            _Pragma("unroll")                                                       \
            for (int ni = 0; ni < 4; ++ni) {                                        \
                int n = wn + ni * 16 + l15;                                         \
                int cpos = ((kk >> 3) + q) ^ (n & 7);                               \
                bf[ni] = *(const short8*)&ldsB[n * BK + 8 * cpos];                  \
            }                                                                       \
            _Pragma("unroll")                                                       \
            for (int mi = 0; mi < 4; ++mi)                                          \
                _Pragma("unroll")                                                   \
                for (int ni = 0; ni < 4; ++ni)                                      \
                    acc[mi][ni] = __builtin_amdgcn_mfma_f32_16x16x32_bf16(          \
                        af[mi], bf[ni], acc[mi][ni], 0, 0, 0);                      \
        }                                                                           \
    }

// ---------------------------------------------------------------- GEMM1
// P1[ks][c][j] = sum_{v in chunk ks} XMT[c][v] * E[v][j]
// A = XMT bf16 (L2-resident, register-staged). B = fp32 E, transpose fused,
// register double-buffered one BK-tile ahead (loads survive the barrier).
__global__ __launch_bounds__(256, 2) void gemm1_fused(const unsigned short* __restrict__ XMT,
                                                      const float* __restrict__ E,
                                                      float* __restrict__ P1) {
    __shared__ __align__(16) unsigned short ldsA[128 * BK];  // [c][v-swizzled]
    __shared__ __align__(16) unsigned short ldsB[128 * BK];  // [j][v-swizzled]
    const int bx = blockIdx.x;
    const int ks = bx & (KS - 1);
    const int n0 = (bx >> 3) * 128;
    const int kb = ks * KCH;
    const int t = threadIdx.x;
    const int w = t >> 6, lane = t & 63, q = lane >> 4, l15 = lane & 15;
    const int wm = (w & 1) * 64, wn = (w >> 1) * 64;
    const int a_row = t >> 1;          // XMT staging: row (=c), full 128 rows
    const int a_c0 = (t & 1) * 4;      // 4 16B chunks per thread
    const int vg = t & 7, jg = t >> 3; // E staging: v-group / j-group

    floatx4 acc[4][4] = {};
    float4 e0[8], e1[8];

#pragma unroll
    for (int rr = 0; rr < 8; ++rr)
        e0[rr] = *(const float4*)&E[(size_t)(kb + vg * 8 + rr) * V + n0 + jg * 4];

    for (int it = 0; it < NI; it += 2) {
        const int k0 = kb + it * BK;
        const int k1 = k0 + BK;
        const int kp = (k1 + BK < kb + KCH) ? (k1 + BK) : (kb + KCH - BK);
        // ---------- stage e0 (k0), prefetch e1 (k0+BK)
        __syncthreads();   // prior frag reads done
        uint4 br[4];
#pragma unroll
        for (int u = 0; u < 4; ++u)
            br[u] = *(const uint4*)&XMT[(size_t)a_row * V + k0 + 8 * (a_c0 + u)];
#pragma unroll
        for (int rr = 0; rr < 8; ++rr)
            e1[rr] = *(const float4*)&E[(size_t)(k1 + vg * 8 + rr) * V + n0 + jg * 4];
#pragma unroll
        for (int u = 0; u < 4; ++u) {
            int c = a_c0 + u;
            *(uint4*)&ldsA[a_row * BK + ((c ^ (a_row & 7))) * 8] = br[u];
        }
        {
            const float* lf = (const float*)e0;
#pragma unroll
            for (int jj = 0; jj < 4; ++jj) {
                int j = jg * 4 + jj;
                short8 b;
#pragma unroll
                for (int rr = 0; rr < 8; ++rr) b[rr] = (short)f2bf(lf[rr * 4 + jj]);
                *(short8*)&ldsB[j * BK + (vg ^ (j & 7)) * 8] = b;
            }
        }
        __syncthreads();   // lgkmcnt drain only — e1 loads stay in flight
        MFMA_BODY;
        // ---------- stage e1 (k0+BK), prefetch e0 (k0+2BK, clamped)
        __syncthreads();
#pragma unroll
        for (int u = 0; u < 4; ++u)
            br[u] = *(const uint4*)&XMT[(size_t)a_row * V + k1 + 8 * (a_c0 + u)];
#pragma unroll
        for (int rr = 0; rr < 8; ++rr)
            e0[rr] = *(const float4*)&E[(size_t)(kp + vg * 8 + rr) * V + n0 + jg * 4];
#pragma unroll
        for (int u = 0; u < 4; ++u) {
            int c = a_c0 + u;
            *(uint4*)&ldsA[a_row * BK + ((c ^ (a_row & 7))) * 8] = br[u];
        }
        {
            const float* lf = (const float*)e1;
#pragma unroll
            for (int jj = 0; jj < 4; ++jj) {
                int j = jg * 4 + jj;
                short8 b;
#pragma unroll
                for (int rr = 0; rr < 8; ++rr) b[rr] = (short)f2bf(lf[rr * 4 + jj]);
                *(short8*)&ldsB[j * BK + (vg ^ (j & 7)) * 8] = b;
            }
        }
        __syncthreads();
        MFMA_BODY;
    }
    float* Pks = P1 + (size_t)ks * C * V;
#pragma unroll
    for (int mi = 0; mi < 4; ++mi) {
        int mrow = wm + mi * 16 + q * 4;
#pragma unroll
        for (int ni = 0; ni < 4; ++ni) {
            int n = n0 + wn + ni * 16 + l15;
#pragma unroll
            for (int r = 0; r < 4; ++r)
                Pks[(size_t)(mrow + r) * V + n] = acc[mi][ni][r];
        }
    }
}

// ---------------------------------------------------------------- GEMM2
// P2[ks][i][c] = sum_{j in chunk ks} E[i][j] * YT[c][j]
// A = fp32 E row-major (register double-buffered). B = YT bf16 (register-staged).
__global__ __launch_bounds__(256, 2) void gemm2_fused(const float* __restrict__ E,
                                                      const unsigned short* __restrict__ YT,
                                                      float* __restrict__ P2) {
    __shared__ __align__(16) unsigned short ldsA[128 * BK];  // [i][j-swizzled]
    __shared__ __align__(16) unsigned short ldsB[128 * BK];  // [c][j-swizzled]
    const int bx = blockIdx.x;
    const int ks = bx & (KS - 1);
    const int m0 = (bx >> 3) * 128;
    const int kb = ks * KCH;
    const int t = threadIdx.x;
    const int w = t >> 6, lane = t & 63, q = lane >> 4, l15 = lane & 15;
    const int wm = (w & 1) * 64, wn = (w >> 1) * 64;
    const int r16 = t >> 2, p = t & 3;   // E staging: rows r16, r16+64; k-quarter p
    const int b_row = t >> 1;            // YT staging
    const int b_c0 = (t & 1) * 4;

    floatx4 acc[4][4] = {};
    float4 e0[8], e1[8];

#pragma unroll
    for (int half = 0; half < 2; ++half)
#pragma unroll
        for (int u = 0; u < 4; ++u)
            e0[half * 4 + u] = *(const float4*)&E[(size_t)(m0 + r16 + half * 64) * V + kb + p * 16 + u * 4];

    for (int it = 0; it < NI; it += 2) {
        const int k0 = kb + it * BK;
        const int k1 = k0 + BK;
        const int kp = (k1 + BK < kb + KCH) ? (k1 + BK) : (kb + KCH - BK);
        // ---------- stage e0 (k0), prefetch e1 (k0+BK)
        __syncthreads();
        uint4 br[4];
#pragma unroll
        for (int u = 0; u < 4; ++u)
            br[u] = *(const uint4*)&YT[(size_t)b_row * V + k0 + 8 * (b_c0 + u)];
#pragma unroll
        for (int half = 0; half < 2; ++half)
#pragma unroll
            for (int u = 0; u < 4; ++u)
                e1[half * 4 + u] = *(const float4*)&E[(size_t)(m0 + r16 + half * 64) * V + k1 + p * 16 + u * 4];
#pragma unroll
        for (int u = 0; u < 4; ++u) {
            int c = b_c0 + u;
            *(uint4*)&ldsB[b_row * BK + ((c ^ (b_row & 7))) * 8] = br[u];
        }
        {
            const float* lf = (const float*)e0;
#pragma unroll
            for (int half = 0; half < 2; ++half) {
                int row = r16 + half * 64;
#pragma unroll
                for (int cc = 0; cc < 2; ++cc) {
                    int c = 2 * p + cc;
                    short8 av;
#pragma unroll
                    for (int e = 0; e < 8; ++e) av[e] = (short)f2bf(lf[half * 16 + cc * 8 + e]);
                    *(short8*)&ldsA[row * BK + ((c ^ (row & 7))) * 8] = av;
                }
            }
        }
        __syncthreads();
        MFMA_BODY;
        // ---------- stage e1 (k0+BK), prefetch e0 (clamped)
        __syncthreads();
#pragma unroll
        for (int u = 0; u < 4; ++u)
            br[u] = *(const uint4*)&YT[(size_t)b_row * V + k1 + 8 * (b_c0 + u)];
#pragma unroll
        for (int half = 0; half < 2; ++half)
#pragma unroll
            for (int u = 0; u < 4; ++u)
                e0[half * 4 + u] = *(const float4*)&E[(size_t)(m0 + r16 + half * 64) * V + kp + p * 16 + u * 4];
#pragma unroll
        for (int u = 0; u < 4; ++u) {
            int c = b_c0 + u;
            *(uint4*)&ldsB[b_row * BK + ((c ^ (b_row & 7))) * 8] = br[u];
        }
        {
            const float* lf = (const float*)e1;
#pragma unroll
            for (int half = 0; half < 2; ++half) {
                int row = r16 + half * 64;
#pragma unroll
                for (int cc = 0; cc < 2; ++cc) {
                    int c = 2 * p + cc;
                    short8 av;
#pragma unroll
                    for (int e = 0; e < 8; ++e) av[e] = (short)f2bf(lf[half * 16 + cc * 8 + e]);
                    *(short8*)&ldsA[row * BK + ((c ^ (row & 7))) * 8] = av;
                }
            }
        }
        __syncthreads();
        MFMA_BODY;
    }
    float* Pks = P2 + (size_t)ks * V * C;
#pragma unroll
    for (int mi = 0; mi < 4; ++mi) {
        int mrow = m0 + wm + mi * 16 + q * 4;
#pragma unroll
        for (int ni = 0; ni < 4; ++ni) {
            int n = wn + ni * 16 + l15;
#pragma unroll
            for (int r = 0; r < 4; ++r)
                Pks[(size_t)(mrow + r) * C + n] = acc[mi][ni][r];
        }
    }
}

// ---------------------------------------------------------------- reductions
__global__ __launch_bounds__(256) void red1(const float* __restrict__ P1,
                                            const float* __restrict__ ev0,
                                            const float* __restrict__ ev1,
                                            const float* __restrict__ dt,
                                            unsigned short* __restrict__ YT) {
    int id = blockIdx.x * 256 + threadIdx.x;
    int c = id >> 10;
    int j0 = (id & 1023) * 8;
    float s[8] = {};
#pragma unroll
    for (int ks = 0; ks < KS; ++ks) {
        const float* row = &P1[((size_t)ks * C + c) * V + j0];
        float4 a = *(const float4*)row;
        float4 b = *(const float4*)(row + 4);
        s[0] += a.x; s[1] += a.y; s[2] += a.z; s[3] += a.w;
        s[4] += b.x; s[5] += b.y; s[6] += b.z; s[7] += b.w;
    }
    float t0 = dt[c], t1 = dt[C + c];
    float a0 = ev0[j0 >> 7] * t0;
    short8 yv;
#pragma unroll
    for (int jj = 0; jj < 8; ++jj) {
        float coef = __expf(-(a0 + ev1[(j0 + jj) & 127] * t1));
        yv[jj] = (short)f2bf(s[jj] * coef);
    }
    *(short8*)&YT[(size_t)c * V + j0] = yv;
}

__global__ __launch_bounds__(256) void red2(const float* __restrict__ P2,
                                            float* __restrict__ out) {
    int id = blockIdx.x * 256 + threadIdx.x;
    size_t off = (size_t)id * 4;
    float4 s = {0.f, 0.f, 0.f, 0.f};
#pragma unroll
    for (int ks = 0; ks < KS; ++ks) {
        float4 v = *(const float4*)&P2[(size_t)ks * V * C + off];
        s.x += v.x; s.y += v.y; s.z += v.z; s.w += v.w;
    }
    *(float4*)&out[off] = s;
}

// ---------------------------------------------------------------- launch
extern "C" void kernel_launch(void* const* d_in, const int* in_sizes, int n_in,
                              void* d_out, int out_size, void* d_ws, size_t ws_size,
                              hipStream_t stream) {
    const float* x    = (const float*)d_in[0];
    const float* mass = (const float*)d_in[3];
    const float* ev0  = (const float*)d_in[4];
    const float* ev1  = (const float*)d_in[5];
    const float* E    = (const float*)d_in[6];
    const float* dt   = (const float*)d_in[7];
    float* out = (float*)d_out;

    // ws: XMT (2 MB) | YT (2 MB) | P (32 MB, reused by both GEMMs)
    unsigned short* XMT = (unsigned short*)d_ws;
    unsigned short* YT  = XMT + (size_t)V * C;
    float* P = (float*)(YT + (size_t)V * C);

    prep_xmt<<<dim3(V / 64, C / 64), 256, 0, stream>>>(x, mass, XMT);
    gemm1_fused<<<(V / 128) * KS, 256, 0, stream>>>(XMT, E, P);
    red1<<<(C * V / 8) / 256, 256, 0, stream>>>(P, ev0, ev1, dt, YT);
    gemm2_fused<<<(V / 128) * KS, 256, 0, stream>>>(E, YT, P);
    red2<<<(V * C / 4) / 256, 256, 0, stream>>>(P, out);
}

// Round 6
// 444.594 us; speedup vs baseline: 1.2714x; 1.0282x over previous
//
#include <hip/hip_runtime.h>
#include <hip/hip_bf16.h>
#include <stdint.h>

#define V 8192
#define C 128
#define KS 8
#define KCH (V / KS)   // 1024
#define BK 64
#define NI (KCH / BK)  // 16 k-iters per chunk

typedef __attribute__((ext_vector_type(8))) short short8;
typedef __attribute__((ext_vector_type(4))) float floatx4;

static __device__ __forceinline__ unsigned short f2bf(float f) {
    unsigned u = __float_as_uint(f);
    u += 0x7FFF + ((u >> 16) & 1);   // RNE
    return (unsigned short)(u >> 16);
}

// ---------------------------------------------------------------- prep
// XMT[c][k] = bf16(x[k][c] * mass[k]); 64x64 LDS tiled transpose
__global__ __launch_bounds__(256) void prep_xmt(const float* __restrict__ x,
                                                const float* __restrict__ mass,
                                                unsigned short* __restrict__ XMT) {
    __shared__ float tile[64][65];
    const int k0 = blockIdx.x * 64;
    const int c0 = blockIdx.y * 64;
    const int t = threadIdx.x;
#pragma unroll
    for (int p = 0; p < 16; ++p) {
        int idx = p * 256 + t;
        int kk = idx >> 6, cc = idx & 63;
        tile[kk][cc] = x[(size_t)(k0 + kk) * C + (c0 + cc)] * mass[k0 + kk];
    }
    __syncthreads();
#pragma unroll
    for (int p = 0; p < 16; ++p) {
        int idx = p * 256 + t;
        int cc = idx >> 6, kk = idx & 63;
        XMT[(size_t)(c0 + cc) * V + (k0 + kk)] = f2bf(tile[kk][cc]);
    }
}

// Shared MFMA inner step (reads swizzled LDS, 32 MFMA/wave)
#define MFMA_BODY                                                                   \
    {                                                                               \
        _Pragma("unroll")                                                           \
        for (int kk = 0; kk < BK; kk += 32) {                                       \
            short8 af[4], bf[4];                                                    \
            _Pragma("unroll")                                                       \
            for (int mi = 0; mi < 4; ++mi) {                                        \
                int m = wm + mi * 16 + l15;                                         \
                int cpos = ((kk >> 3) + q) ^ (m & 7);                               \
                af[mi] = *(const short8*)&ldsA[m * BK + 8 * cpos];                  \
            }                                                                       \
            _Pragma("unroll")                                                       \
            for (int ni = 0; ni < 4; ++ni) {                                        \
                int n = wn + ni * 16 + l15;                                         \
                int cpos = ((kk >> 3) + q) ^ (n & 7);                               \
                bf[ni] = *(const short8*)&ldsB[n * BK + 8 * cpos];                  \
            }                                                                       \
            _Pragma("unroll")                                                       \
            for (int mi = 0; mi < 4; ++mi)                                          \
                _Pragma("unroll")                                                   \
                for (int ni = 0; ni < 4; ++ni)                                      \
                    acc[mi][ni] = __builtin_amdgcn_mfma_f32_16x16x32_bf16(          \
                        af[mi], bf[ni], acc[mi][ni], 0, 0, 0);                      \
        }                                                                           \
    }

// ---------------------------------------------------------------- GEMM1
// P1[ks][c][j] = sum_{v in chunk ks} XMT[c][v] * E[v][j]
// A = XMT bf16 (L2-resident). B = fp32 E, transpose fused into staging,
// register double-buffered one BK-tile ahead.
// Lane maps chosen so every VMEM instruction covers contiguous >=128B segments.
__global__ __launch_bounds__(256, 2) void gemm1_fused(const unsigned short* __restrict__ XMT,
                                                      const float* __restrict__ E,
                                                      float* __restrict__ P1) {
    __shared__ __align__(16) unsigned short ldsA[128 * BK];  // [c][v-swizzled]
    __shared__ __align__(16) unsigned short ldsB[128 * BK];  // [j][v-swizzled]
    const int bx = blockIdx.x;
    const int ks = bx & (KS - 1);
    const int n0 = (bx >> 3) * 128;
    const int kb = ks * KCH;
    const int t = threadIdx.x;
    const int w = t >> 6, lane = t & 63, q = lane >> 4, l15 = lane & 15;
    const int wm = (w & 1) * 64, wn = (w >> 1) * 64;
    // XMT staging: per inst, 8 lanes cover one full 128B row; rows r8+32u
    const int acp = t & 7;          // 16B chunk in row
    const int ar8 = t >> 3;         // base row 0..31
    // E staging: per inst, 8 lanes cover 128B row segment; 8 rows per inst
    const int jg = (t & 7) | ((t >> 6) << 3);  // j-chunk 0..31 (4 cols)
    const int vq = (t >> 3) & 7;               // v-octet

    floatx4 acc[4][4] = {};
    float4 e0[8], e1[8];

#pragma unroll
    for (int rr = 0; rr < 8; ++rr)
        e0[rr] = *(const float4*)&E[(size_t)(kb + vq * 8 + rr) * V + n0 + jg * 4];

    for (int it = 0; it < NI; it += 2) {
        const int k0 = kb + it * BK;
        const int k1 = k0 + BK;
        const int kp = (k1 + BK < kb + KCH) ? (k1 + BK) : (kb + KCH - BK);
        // ---------- stage e0 (k0), prefetch e1 (k0+BK)
        __syncthreads();   // prior frag reads done
        uint4 br[4];
#pragma unroll
        for (int u = 0; u < 4; ++u)
            br[u] = *(const uint4*)&XMT[(size_t)(ar8 + 32 * u) * V + k0 + acp * 8];
#pragma unroll
        for (int rr = 0; rr < 8; ++rr)
            e1[rr] = *(const float4*)&E[(size_t)(k1 + vq * 8 + rr) * V + n0 + jg * 4];
#pragma unroll
        for (int u = 0; u < 4; ++u) {
            int r = ar8 + 32 * u;
            *(uint4*)&ldsA[r * BK + ((acp ^ (r & 7))) * 8] = br[u];
        }
        {
            const float* lf = (const float*)e0;
#pragma unroll
            for (int jj = 0; jj < 4; ++jj) {
                int j = jg * 4 + jj;
                short8 b;
#pragma unroll
                for (int rr = 0; rr < 8; ++rr) b[rr] = (short)f2bf(lf[rr * 4 + jj]);
                *(short8*)&ldsB[j * BK + (vq ^ (j & 7)) * 8] = b;
            }
        }
        __syncthreads();   // e1 loads stay in flight (VGPR-destined)
        MFMA_BODY;
        // ---------- stage e1 (k0+BK), prefetch e0 (k0+2BK, clamped)
        __syncthreads();
#pragma unroll
        for (int u = 0; u < 4; ++u)
            br[u] = *(const uint4*)&XMT[(size_t)(ar8 + 32 * u) * V + k1 + acp * 8];
#pragma unroll
        for (int rr = 0; rr < 8; ++rr)
            e0[rr] = *(const float4*)&E[(size_t)(kp + vq * 8 + rr) * V + n0 + jg * 4];
#pragma unroll
        for (int u = 0; u < 4; ++u) {
            int r = ar8 + 32 * u;
            *(uint4*)&ldsA[r * BK + ((acp ^ (r & 7))) * 8] = br[u];
        }
        {
            const float* lf = (const float*)e1;
#pragma unroll
            for (int jj = 0; jj < 4; ++jj) {
                int j = jg * 4 + jj;
                short8 b;
#pragma unroll
                for (int rr = 0; rr < 8; ++rr) b[rr] = (short)f2bf(lf[rr * 4 + jj]);
                *(short8*)&ldsB[j * BK + (vq ^ (j & 7)) * 8] = b;
            }
        }
        __syncthreads();
        MFMA_BODY;
    }
    float* Pks = P1 + (size_t)ks * C * V;
#pragma unroll
    for (int mi = 0; mi < 4; ++mi) {
        int mrow = wm + mi * 16 + q * 4;
#pragma unroll
        for (int ni = 0; ni < 4; ++ni) {
            int n = n0 + wn + ni * 16 + l15;
#pragma unroll
            for (int r = 0; r < 4; ++r)
                Pks[(size_t)(mrow + r) * V + n] = acc[mi][ni][r];
        }
    }
}

// ---------------------------------------------------------------- GEMM2
// P2[ks][i][c] = sum_{j in chunk ks} E[i][j] * YT[c][j]
// A = fp32 E row-major (register double-buffered, coalesced 256B row reads).
// B = YT bf16 (L2-resident, coalesced 128B row reads).
__global__ __launch_bounds__(256, 2) void gemm2_fused(const float* __restrict__ E,
                                                      const unsigned short* __restrict__ YT,
                                                      float* __restrict__ P2) {
    __shared__ __align__(16) unsigned short ldsA[128 * BK];  // [i][j-swizzled]
    __shared__ __align__(16) unsigned short ldsB[128 * BK];  // [c][j-swizzled]
    const int bx = blockIdx.x;
    const int ks = bx & (KS - 1);
    const int m0 = (bx >> 3) * 128;
    const int kb = ks * KCH;
    const int t = threadIdx.x;
    const int w = t >> 6, lane = t & 63, q = lane >> 4, l15 = lane & 15;
    const int wm = (w & 1) * 64, wn = (w >> 1) * 64;
    // E staging: per inst, 16 lanes cover one full 256B row; 4 rows per inst
    const int ach = t & 15;        // 16B chunk in row (4 fp32: cols ach*4..+3)
    const int ar  = t >> 4;        // base row 0..15; rows ar+16u
    // YT staging: per inst, 8 lanes cover one full 128B row; 8 rows per inst
    const int bcp = t & 7;
    const int br8 = t >> 3;

    floatx4 acc[4][4] = {};
    float4 e0[8], e1[8];

#pragma unroll
    for (int u = 0; u < 8; ++u)
        e0[u] = *(const float4*)&E[(size_t)(m0 + ar + 16 * u) * V + kb + ach * 4];

    for (int it = 0; it < NI; it += 2) {
        const int k0 = kb + it * BK;
        const int k1 = k0 + BK;
        const int kp = (k1 + BK < kb + KCH) ? (k1 + BK) : (kb + KCH - BK);
        // ---------- stage e0 (k0), prefetch e1 (k0+BK)
        __syncthreads();
        uint4 br[4];
#pragma unroll
        for (int u = 0; u < 4; ++u)
            br[u] = *(const uint4*)&YT[(size_t)(br8 + 32 * u) * V + k0 + bcp * 8];
#pragma unroll
        for (int u = 0; u < 8; ++u)
            e1[u] = *(const float4*)&E[(size_t)(m0 + ar + 16 * u) * V + k1 + ach * 4];
#pragma unroll
        for (int u = 0; u < 4; ++u) {
            int r = br8 + 32 * u;
            *(uint4*)&ldsB[r * BK + ((bcp ^ (r & 7))) * 8] = br[u];
        }
        {
            const float* lf = (const float*)e0;
#pragma unroll
            for (int u = 0; u < 8; ++u) {
                int row = ar + 16 * u;
                ushort4 av;
                av.x = f2bf(lf[u * 4 + 0]); av.y = f2bf(lf[u * 4 + 1]);
                av.z = f2bf(lf[u * 4 + 2]); av.w = f2bf(lf[u * 4 + 3]);
                *(ushort4*)&ldsA[row * BK + ((ach >> 1) ^ (row & 7)) * 8 + (ach & 1) * 4] = av;
            }
        }
        __syncthreads();
        MFMA_BODY;
        // ---------- stage e1 (k0+BK), prefetch e0 (clamped)
        __syncthreads();
#pragma unroll
        for (int u = 0; u < 4; ++u)
            br[u] = *(const uint4*)&YT[(size_t)(br8 + 32 * u) * V + k1 + bcp * 8];
#pragma unroll
        for (int u = 0; u < 8; ++u)
            e0[u] = *(const float4*)&E[(size_t)(m0 + ar + 16 * u) * V + kp + ach * 4];
#pragma unroll
        for (int u = 0; u < 4; ++u) {
            int r = br8 + 32 * u;
            *(uint4*)&ldsB[r * BK + ((bcp ^ (r & 7))) * 8] = br[u];
        }
        {
            const float* lf = (const float*)e1;
#pragma unroll
            for (int u = 0; u < 8; ++u) {
                int row = ar + 16 * u;
                ushort4 av;
                av.x = f2bf(lf[u * 4 + 0]); av.y = f2bf(lf[u * 4 + 1]);
                av.z = f2bf(lf[u * 4 + 2]); av.w = f2bf(lf[u * 4 + 3]);
                *(ushort4*)&ldsA[row * BK + ((ach >> 1) ^ (row & 7)) * 8 + (ach & 1) * 4] = av;
            }
        }
        __syncthreads();
        MFMA_BODY;
    }
    float* Pks = P2 + (size_t)ks * V * C;
#pragma unroll
    for (int mi = 0; mi < 4; ++mi) {
        int mrow = m0 + wm + mi * 16 + q * 4;
#pragma unroll
        for (int ni = 0; ni < 4; ++ni) {
            int n = wn + ni * 16 + l15;
#pragma unroll
            for (int r = 0; r < 4; ++r)
                Pks[(size_t)(mrow + r) * C + n] = acc[mi][ni][r];
        }
    }
}

// ---------------------------------------------------------------- reductions
__global__ __launch_bounds__(256) void red1(const float* __restrict__ P1,
                                            const float* __restrict__ ev0,
                                            const float* __restrict__ ev1,
                                            const float* __restrict__ dt,
                                            unsigned short* __restrict__ YT) {
    int id = blockIdx.x * 256 + threadIdx.x;
    int c = id >> 10;
    int j0 = (id & 1023) * 8;
    float s[8] = {};
#pragma unroll
    for (int ks = 0; ks < KS; ++ks) {
        const float* row = &P1[((size_t)ks * C + c) * V + j0];
        float4 a = *(const float4*)row;
        float4 b = *(const float4*)(row + 4);
        s[0] += a.x; s[1] += a.y; s[2] += a.z; s[3] += a.w;
        s[4] += b.x; s[5] += b.y; s[6] += b.z; s[7] += b.w;
    }
    float t0 = dt[c], t1 = dt[C + c];
    float a0 = ev0[j0 >> 7] * t0;
    short8 yv;
#pragma unroll
    for (int jj = 0; jj < 8; ++jj) {
        float coef = __expf(-(a0 + ev1[(j0 + jj) & 127] * t1));
        yv[jj] = (short)f2bf(s[jj] * coef);
    }
    *(short8*)&YT[(size_t)c * V + j0] = yv;
}

__global__ __launch_bounds__(256) void red2(const float* __restrict__ P2,
                                            float* __restrict__ out) {
    int id = blockIdx.x * 256 + threadIdx.x;
    size_t off = (size_t)id * 4;
    float4 s = {0.f, 0.f, 0.f, 0.f};
#pragma unroll
    for (int ks = 0; ks < KS; ++ks) {
        float4 v = *(const float4*)&P2[(size_t)ks * V * C + off];
        s.x += v.x; s.y += v.y; s.z += v.z; s.w += v.w;
    }
    *(float4*)&out[off] = s;
}

// ---------------------------------------------------------------- launch
extern "C" void kernel_launch(void* const* d_in, const int* in_sizes, int n_in,
                              void* d_out, int out_size, void* d_ws, size_t ws_size,
                              hipStream_t stream) {
    const float* x    = (const float*)d_in[0];
    const float* mass = (const float*)d_in[3];
    const float* ev0  = (const float*)d_in[4];
    const float* ev1  = (const float*)d_in[5];
    const float* E    = (const float*)d_in[6];
    const float* dt   = (const float*)d_in[7];
    float* out = (float*)d_out;

    // ws: XMT (2 MB) | YT (2 MB) | P (32 MB, reused by both GEMMs)
    unsigned short* XMT = (unsigned short*)d_ws;
    unsigned short* YT  = XMT + (size_t)V * C;
    float* P = (float*)(YT + (size_t)V * C);

    prep_xmt<<<dim3(V / 64, C / 64), 256, 0, stream>>>(x, mass, XMT);
    gemm1_fused<<<(V / 128) * KS, 256, 0, stream>>>(XMT, E, P);
    red1<<<(C * V / 8) / 256, 256, 0, stream>>>(P, ev0, ev1, dt, YT);
    gemm2_fused<<<(V / 128) * KS, 256, 0, stream>>>(E, YT, P);
    red2<<<(V * C / 4) / 256, 256, 0, stream>>>(P, out);
}